// Round 19
// baseline (41.089 us; speedup 1.0000x reference)
//
#include <hip/hip_runtime.h>
#include <hip/hip_bf16.h>

typedef float f32x4 __attribute__((ext_vector_type(4)));
typedef short bf16x8 __attribute__((ext_vector_type(8)));
typedef _Float16 f16x8 __attribute__((ext_vector_type(8)));

#define MFMA16  __builtin_amdgcn_mfma_f32_16x16x32_bf16
#define MFMA16F __builtin_amdgcn_mfma_f32_16x16x32_f16

static constexpr int KDIM = 1700;
static constexpr int NKT2 = 56;         // padded k-tiles: 54 real (53 ragged) + 2 zero
static constexpr float BETA = 0.9f;
static constexpr float THRESH = 1.0f;

// fp32 -> bf16 hi + bf16 lo (residual) — used in the recurrence (unchanged)
__device__ __forceinline__ void split_bf(float f, short& hi, short& lo) {
    __hip_bfloat16 h = __float2bfloat16(f);
    float r = f - __bfloat162float(h);          // exact in fp32
    __hip_bfloat16 l = __float2bfloat16(r);
    hi = (short)__builtin_bit_cast(unsigned short, h);
    lo = (short)__builtin_bit_cast(unsigned short, l);
}

__device__ __forceinline__ void split8(f32x4 a, f32x4 b, bf16x8& hi, bf16x8& lo) {
    #pragma unroll
    for (int i = 0; i < 4; ++i) { short h, l; split_bf(a[i], h, l); hi[i] = h; lo[i] = l; }
    #pragma unroll
    for (int i = 0; i < 4; ++i) { short h, l; split_bf(b[i], h, l); hi[4 + i] = h; lo[4 + i] = l; }
}

// fp32 -> fp16 hi + fp16 lo (residual): x representation error ~2^-22 relative
__device__ __forceinline__ void split8h(f32x4 a, f32x4 b, f16x8& hi, f16x8& lo) {
    #pragma unroll
    for (int i = 0; i < 4; ++i) {
        _Float16 h = (_Float16)a[i];
        hi[i] = h; lo[i] = (_Float16)(a[i] - (float)h);
    }
    #pragma unroll
    for (int i = 0; i < 4; ++i) {
        _Float16 h = (_Float16)b[i];
        hi[4 + i] = h; lo[4 + i] = (_Float16)(b[i] - (float)h);
    }
}

// W1 [64][1700] f32 -> ONE fp16 plane in MFMA-B-fragment order, 56 k-tiles
// (k >= 1700 zero-padded).
__global__ void w1_relayout(const float* __restrict__ W1, _Float16* __restrict__ WT) {
    const int g    = blockIdx.x * 256 + threadIdx.x;   // 0 .. 56*256-1
    const int kt   = g >> 8;
    const int nt   = (g >> 6) & 3;
    const int lane = g & 63;
    const int n    = nt * 16 + (lane & 15);
    const int kb   = kt * 32 + (lane >> 4) * 8;
    f16x8 v;
    #pragma unroll
    for (int i = 0; i < 8; ++i) {
        const int k = kb + i;
        v[i] = (k < KDIM) ? (_Float16)W1[n * KDIM + k] : (_Float16)0.f;
    }
    *(f16x8*)(WT + (size_t)g * 8) = v;
}

__device__ __forceinline__ void gll16(const void* src, const void* lds_dst) {
    __builtin_amdgcn_global_load_lds(
        (const __attribute__((address_space(1))) unsigned int*)src,
        (__attribute__((address_space(3))) unsigned int*)lds_dst, 16, 0, 0);
}

// ---------------- fused kernel: cur1 GEMM (fp16 W, deep pipeline) + LIF ------
// r18's kernel with DEEPENED prefetch: W quad-buffer (W(I) issued 4 steps
// ahead), x ring-of-5 (x(I) issued 5 steps ahead) — attacks the per-step
// exposed-latency wall that r18's -3.3us (issue-cost only) left standing.
// Ledger (flattened issue timeline W0,x0,W1,x1,W2,x2,W3,x3,x4 | step I:
// stageW(I+4), xload(I+5)): steps 0-9 wait vmcnt(28) = drain {x(I),W(I)};
// tail 24/16/8/0. Hazard: stageW(I+4) overwrites buf I&3 only after the
// lgkmcnt(0) that guarantees step I's WC ds_reads completed (r14 invariant).
__global__ __launch_bounds__(256, 2) void snn_fused(
    const float* __restrict__ x, const _Float16* __restrict__ WT,
    const float* __restrict__ b1, const float* __restrict__ W2,
    const float* __restrict__ b2, const float* __restrict__ W3,
    const float* __restrict__ b3, const int* __restrict__ nsp,
    float* __restrict__ out)
{
    __shared__ __align__(16) char smemraw[65536];   // W 64KB quad-buf (red aliased)
    _Float16* ldsW = (_Float16*)smemraw;
    float (*red)[32][68] = (float (*)[32][68])smemraw;

    const int tid = threadIdx.x;
    const int wid = tid >> 6;
    const int lane = tid & 63;
    const int l15 = lane & 15;
    const int g4  = lane >> 4;
    const int kg  = g4 * 8;
    const int rowBase = blockIdx.x * 32;
    const int t0  = wid * 14;

    const float* xr0 = x + (size_t)(rowBase + l15) * KDIM;
    const float* xr1 = xr0 + (size_t)16 * KDIM;
    const _Float16* pW = WT + (size_t)t0 * 2048 + lane * 8;   // per-lane W src
    _Float16* myLds = ldsW + wid * 8192;            // 16KB/wave (4 x 4KB bufs)

    struct XB { f32x4 a0, a1, b0, b1; };
    // x fragment load via inline asm (pinned issue; consumption guarded by the
    // counted vmcnt). Clamped in-row for k >= 1700 (W there is zero).
    auto xload = [&](int t, XB& xb) {
        const int k1 = t * 32 + kg;
        const int kc1 = (k1 <= 1696) ? k1 : 1664;
        const int kc2 = (k1 + 4 <= 1696) ? k1 + 4 : 1664;
        const float* p0 = xr0 + kc1;
        const float* p1 = xr0 + kc2;
        const float* p2 = xr1 + kc1;
        const float* p3 = xr1 + kc2;
        asm volatile("global_load_dwordx4 %0, %1, off" : "=v"(xb.a0) : "v"(p0));
        asm volatile("global_load_dwordx4 %0, %1, off" : "=v"(xb.a1) : "v"(p1));
        asm volatile("global_load_dwordx4 %0, %1, off" : "=v"(xb.b0) : "v"(p2));
        asm volatile("global_load_dwordx4 %0, %1, off" : "=v"(xb.b1) : "v"(p3));
    };
    // stage tile (t0+i) into wave-private LDS buffer `buf` (4 x 1KB, vmcnt)
    auto stageW = [&](int i, int buf) {
        _Float16* dstb = myLds + buf * 2048;
        #pragma unroll
        for (int q = 0; q < 4; ++q)
            gll16(pW + (size_t)i * 2048 + q * 512, dstb + q * 512);
    };

    f32x4 acc[2][4] = {};
    XB x0, x1, x2, x3, x4;

    // prologue issue order: W0,x0,W1,x1,W2,x2,W3,x3,x4  (36 outstanding)
    stageW(0, 0); xload(t0 + 0, x0);
    stageW(1, 1); xload(t0 + 1, x1);
    stageW(2, 2); xload(t0 + 2, x2);
    stageW(3, 3); xload(t0 + 3, x3);
    xload(t0 + 4, x4);

#define GSTEP(I, XC, WAITN)                                                    \
    {                                                                          \
        asm volatile("s_waitcnt vmcnt(" #WAITN ")" ::: "memory");              \
        __builtin_amdgcn_sched_barrier(0);                                     \
        const _Float16* rb = myLds + ((I) & 3) * 2048;                         \
        f16x8 WC[4];                                                           \
        _Pragma("unroll")                                                      \
        for (int q = 0; q < 4; ++q)                                            \
            WC[q] = *(const f16x8*)(rb + q * 512 + lane * 8);                  \
        f16x8 ah0, al0, ah1, al1;                                              \
        split8h(XC.a0, XC.a1, ah0, al0);                                       \
        split8h(XC.b0, XC.b1, ah1, al1);                                       \
        asm volatile("s_waitcnt lgkmcnt(0)" ::: "memory");                     \
        __builtin_amdgcn_sched_barrier(0);                                     \
        if constexpr ((I) + 4 < 14) stageW((I) + 4, (I) & 3);                  \
        if constexpr ((I) + 5 < 14) xload(t0 + (I) + 5, XC);                   \
        __builtin_amdgcn_sched_barrier(0);                                     \
        _Pragma("unroll")                                                      \
        for (int nt = 0; nt < 4; ++nt) {                                       \
            acc[0][nt] = MFMA16F(ah0, WC[nt], acc[0][nt], 0, 0, 0);            \
            acc[0][nt] = MFMA16F(al0, WC[nt], acc[0][nt], 0, 0, 0);            \
            acc[1][nt] = MFMA16F(ah1, WC[nt], acc[1][nt], 0, 0, 0);            \
            acc[1][nt] = MFMA16F(al1, WC[nt], acc[1][nt], 0, 0, 0);            \
        }                                                                      \
    }

    GSTEP(0,  x0, 28)
    GSTEP(1,  x1, 28)
    GSTEP(2,  x2, 28)
    GSTEP(3,  x3, 28)
    GSTEP(4,  x4, 28)
    GSTEP(5,  x0, 28)
    GSTEP(6,  x1, 28)
    GSTEP(7,  x2, 28)
    GSTEP(8,  x3, 28)
    GSTEP(9,  x4, 28)
    GSTEP(10, x0, 24)
    GSTEP(11, x1, 16)
    GSTEP(12, x2, 8)
    GSTEP(13, x3, 0)
#undef GSTEP

    // ldsW regions of different waves alias red[] -> sync BEFORE overwriting
    __syncthreads();

    // partials -> LDS (C-layout: row = mt*16 + g4*4 + j, col = nt*16 + l15)
    #pragma unroll
    for (int mt = 0; mt < 2; ++mt)
        #pragma unroll
        for (int nt = 0; nt < 4; ++nt)
            #pragma unroll
            for (int j = 0; j < 4; ++j)
                red[wid][mt * 16 + g4 * 4 + j][nt * 16 + l15] = acc[mt][nt][j];
    __syncthreads();

    // reduce 4 k-partials + b1 into red[0] (disjoint (rr,seg) slots: race-free)
    {
        const int rr  = tid >> 3;
        const int seg = tid & 7;
        f32x4 s0 = *(const f32x4*)(b1 + seg * 8);
        f32x4 s1 = *(const f32x4*)(b1 + seg * 8 + 4);
        #pragma unroll
        for (int p = 0; p < 4; ++p) {
            s0 += *(const f32x4*)&red[p][rr][seg * 8];
            s1 += *(const f32x4*)&red[p][rr][seg * 8 + 4];
        }
        *(f32x4*)&red[0][rr][seg * 8]     = s0;
        *(f32x4*)&red[0][rr][seg * 8 + 4] = s1;
    }
    __syncthreads();
    if (wid >= 2) return;                     // waves 2,3 done (no barriers below)

    // ---------------- phase 2: 20-step LIF recurrence, all in registers ------
    const int lrow = wid * 16 + l15;

    float c1[2][8], c1m1[2][8];
    #pragma unroll
    for (int kt = 0; kt < 2; ++kt) {
        f32x4 u0 = *(const f32x4*)&red[0][lrow][kt * 32 + kg];
        f32x4 u1 = *(const f32x4*)&red[0][lrow][kt * 32 + kg + 4];
        #pragma unroll
        for (int i = 0; i < 4; ++i) {
            c1[kt][i] = u0[i];     c1[kt][4 + i] = u1[i];
            c1m1[kt][i] = u0[i] - THRESH; c1m1[kt][4 + i] = u1[i] - THRESH;
        }
    }

    bf16x8 W2hf[2][2], W2lf[2][2];
    #pragma unroll
    for (int rt = 0; rt < 2; ++rt)
        #pragma unroll
        for (int kt = 0; kt < 2; ++kt) {
            const float* wp = W2 + (rt * 16 + l15) * 64 + kt * 32 + kg;
            split8(*(const f32x4*)wp, *(const f32x4*)(wp + 4), W2hf[rt][kt], W2lf[rt][kt]);
        }

    float b2v[2][4], b2m1[2][4], w3a[2][4], w3b[2][4];
    #pragma unroll
    for (int nt = 0; nt < 2; ++nt)
        #pragma unroll
        for (int j = 0; j < 4; ++j) {
            const int o = nt * 16 + g4 * 4 + j;
            b2v[nt][j]  = b2[o];
            b2m1[nt][j] = b2[o] - THRESH;
            w3a[nt][j] = W3[o];
            w3b[nt][j] = W3[32 + o];
        }

    float m1[2][8] = {};
    float m2[2][4] = {};
    const int ns = nsp[0];
    for (int s = 0; s < ns; ++s) {
        bf16x8 mh[2], ml[2];
        #pragma unroll
        for (int kt = 0; kt < 2; ++kt)
            #pragma unroll
            for (int i = 0; i < 8; ++i) {
                float m = m1[kt][i];
                m = __builtin_fmaf(BETA, m, (m > THRESH) ? c1m1[kt][i] : c1[kt][i]);
                m1[kt][i] = m;
                short h, l; split_bf(m, h, l);
                mh[kt][i] = h; ml[kt][i] = l;
            }
        f32x4 a2[2][2] = {};
        #pragma unroll
        for (int rt = 0; rt < 2; ++rt)
            #pragma unroll
            for (int kt = 0; kt < 2; ++kt) {
                a2[rt][kt] = MFMA16(W2hf[rt][kt], mh[kt], a2[rt][kt], 0, 0, 0);
                a2[rt][kt] = MFMA16(W2lf[rt][kt], mh[kt], a2[rt][kt], 0, 0, 0);
                a2[rt][kt] = MFMA16(W2hf[rt][kt], ml[kt], a2[rt][kt], 0, 0, 0);
            }
        #pragma unroll
        for (int nt = 0; nt < 2; ++nt) {
            f32x4 c2 = a2[nt][0] + a2[nt][1];
            #pragma unroll
            for (int j = 0; j < 4; ++j) {
                float m = m2[nt][j];
                m2[nt][j] = __builtin_fmaf(
                    BETA, m, c2[j] + ((m > THRESH) ? b2m1[nt][j] : b2v[nt][j]));
            }
        }
    }

    float p0 = 0.f, p1 = 0.f;
    #pragma unroll
    for (int nt = 0; nt < 2; ++nt)
        #pragma unroll
        for (int j = 0; j < 4; ++j) {
            p0 = __builtin_fmaf(m2[nt][j], w3a[nt][j], p0);
            p1 = __builtin_fmaf(m2[nt][j], w3b[nt][j], p1);
        }
    p0 += __shfl_xor(p0, 16); p0 += __shfl_xor(p0, 32);
    p1 += __shfl_xor(p1, 16); p1 += __shfl_xor(p1, 32);
    if (lane < 16) {
        const size_t row = rowBase + lrow;
        out[row * 2 + 0] = p0 + b3[0];
        out[row * 2 + 1] = p1 + b3[1];
    }
}

extern "C" void kernel_launch(void* const* d_in, const int* in_sizes, int n_in,
                              void* d_out, int out_size, void* d_ws, size_t ws_size,
                              hipStream_t stream) {
    const float* x  = (const float*)d_in[0];
    const float* W1 = (const float*)d_in[1];
    const float* b1 = (const float*)d_in[2];
    const float* W2 = (const float*)d_in[3];
    const float* b2 = (const float*)d_in[4];
    const float* W3 = (const float*)d_in[5];
    const float* b3 = (const float*)d_in[6];
    const int*   ns = (const int*)d_in[7];
    float* o = (float*)d_out;

    const int B = in_sizes[0] / KDIM;              // 16384
    _Float16* WT = (_Float16*)d_ws;                // [56][2048] fp16 (224 KB)

    w1_relayout<<<NKT2, 256, 0, stream>>>(W1, WT);
    snn_fused<<<B / 32, 256, 0, stream>>>(x, WT, b1, W2, b2, W3, b3, ns, o);
}

// Round 20
// 41.023 us; speedup vs baseline: 1.0016x; 1.0016x over previous
//
#include <hip/hip_runtime.h>
#include <hip/hip_bf16.h>

typedef float f32x4 __attribute__((ext_vector_type(4)));
typedef short bf16x8 __attribute__((ext_vector_type(8)));
typedef _Float16 f16x8 __attribute__((ext_vector_type(8)));

#define MFMA16  __builtin_amdgcn_mfma_f32_16x16x32_bf16
#define MFMA16F __builtin_amdgcn_mfma_f32_16x16x32_f16

static constexpr int KDIM = 1700;
static constexpr int NKT2 = 56;         // padded k-tiles: 54 real (53 ragged) + 2 zero
static constexpr float BETA = 0.9f;
static constexpr float THRESH = 1.0f;

// fp32 -> bf16 hi + bf16 lo (residual) — used in the recurrence (unchanged)
__device__ __forceinline__ void split_bf(float f, short& hi, short& lo) {
    __hip_bfloat16 h = __float2bfloat16(f);
    float r = f - __bfloat162float(h);          // exact in fp32
    __hip_bfloat16 l = __float2bfloat16(r);
    hi = (short)__builtin_bit_cast(unsigned short, h);
    lo = (short)__builtin_bit_cast(unsigned short, l);
}

__device__ __forceinline__ void split8(f32x4 a, f32x4 b, bf16x8& hi, bf16x8& lo) {
    #pragma unroll
    for (int i = 0; i < 4; ++i) { short h, l; split_bf(a[i], h, l); hi[i] = h; lo[i] = l; }
    #pragma unroll
    for (int i = 0; i < 4; ++i) { short h, l; split_bf(b[i], h, l); hi[4 + i] = h; lo[4 + i] = l; }
}

// fp32 -> fp16 hi + fp16 lo (residual): x representation error ~2^-22 relative
__device__ __forceinline__ void split8h(f32x4 a, f32x4 b, f16x8& hi, f16x8& lo) {
    #pragma unroll
    for (int i = 0; i < 4; ++i) {
        _Float16 h = (_Float16)a[i];
        hi[i] = h; lo[i] = (_Float16)(a[i] - (float)h);
    }
    #pragma unroll
    for (int i = 0; i < 4; ++i) {
        _Float16 h = (_Float16)b[i];
        hi[4 + i] = h; lo[4 + i] = (_Float16)(b[i] - (float)h);
    }
}

// W1 [64][1700] f32 -> ONE fp16 plane in MFMA-B-fragment order, 56 k-tiles
// (k >= 1700 zero-padded).
__global__ void w1_relayout(const float* __restrict__ W1, _Float16* __restrict__ WT) {
    const int g    = blockIdx.x * 256 + threadIdx.x;   // 0 .. 56*256-1
    const int kt   = g >> 8;
    const int nt   = (g >> 6) & 3;
    const int lane = g & 63;
    const int n    = nt * 16 + (lane & 15);
    const int kb   = kt * 32 + (lane >> 4) * 8;
    f16x8 v;
    #pragma unroll
    for (int i = 0; i < 8; ++i) {
        const int k = kb + i;
        v[i] = (k < KDIM) ? (_Float16)W1[n * KDIM + k] : (_Float16)0.f;
    }
    *(f16x8*)(WT + (size_t)g * 8) = v;
}

__device__ __forceinline__ void gll16(const void* src, const void* lds_dst) {
    __builtin_amdgcn_global_load_lds(
        (const __attribute__((address_space(1))) unsigned int*)src,
        (__attribute__((address_space(3))) unsigned int*)lds_dst, 16, 0, 0);
}

// ---------------- fused kernel: cur1 GEMM (fp16 W, merged steps) + LIF -------
// r18's pipeline with steps MERGED 2:1 — 7 double-steps of {8 W gll16, 8 x
// loads, 32 MFMA}. Total VMEM instr count unchanged (r18's proven variable);
// per-step overhead (vmcnt wait + 2x lgkmcnt + sched barriers) halves 14->7.
// Ledger (flattened): prologue W2(0)[8],X2(0)[8],W2(1)[8],X2(1)[8] = 32
// outstanding; steps 0-5 wait vmcnt(16) = drain exactly W2(I)+X2(I); step 6
// waits 0. Hazard (r14): WC ds_reads of buf I&1 complete (lgkmcnt 0) BEFORE
// stageW2(I+2) overwrites it.
__global__ __launch_bounds__(256, 2) void snn_fused(
    const float* __restrict__ x, const _Float16* __restrict__ WT,
    const float* __restrict__ b1, const float* __restrict__ W2,
    const float* __restrict__ b2, const float* __restrict__ W3,
    const float* __restrict__ b3, const int* __restrict__ nsp,
    float* __restrict__ out)
{
    __shared__ __align__(16) char smemraw[65536];   // W 64KB (2 bufs x 8KB/wave)
    _Float16* ldsW = (_Float16*)smemraw;
    float (*red)[32][68] = (float (*)[32][68])smemraw;

    const int tid = threadIdx.x;
    const int wid = tid >> 6;
    const int lane = tid & 63;
    const int l15 = lane & 15;
    const int g4  = lane >> 4;
    const int kg  = g4 * 8;
    const int rowBase = blockIdx.x * 32;
    const int t0  = wid * 14;                  // 14 tiles = 7 double-tiles

    const float* xr0 = x + (size_t)(rowBase + l15) * KDIM;
    const float* xr1 = xr0 + (size_t)16 * KDIM;
    const _Float16* pW = WT + (size_t)t0 * 2048 + lane * 8;   // per-lane W src
    _Float16* myLds = ldsW + wid * 8192;       // 16KB/wave (2 x 8KB bufs)

    struct XB2 { f32x4 v[8]; };                // two tiles' x fragments
    // load x for double-tile d (tiles t0+2d, t0+2d+1); asm-pinned issue,
    // consumption guarded by the counted vmcnt. Clamp in-row for k >= 1700.
    auto xload2 = [&](int d, XB2& xb) {
        #pragma unroll
        for (int j = 0; j < 2; ++j) {
            const int t  = t0 + 2 * d + j;
            const int k1 = t * 32 + kg;
            const int kc1 = (k1 <= 1696) ? k1 : 1664;
            const int kc2 = (k1 + 4 <= 1696) ? k1 + 4 : 1664;
            const float* p0 = xr0 + kc1;
            const float* p1 = xr0 + kc2;
            const float* p2 = xr1 + kc1;
            const float* p3 = xr1 + kc2;
            asm volatile("global_load_dwordx4 %0, %1, off" : "=v"(xb.v[4*j+0]) : "v"(p0));
            asm volatile("global_load_dwordx4 %0, %1, off" : "=v"(xb.v[4*j+1]) : "v"(p1));
            asm volatile("global_load_dwordx4 %0, %1, off" : "=v"(xb.v[4*j+2]) : "v"(p2));
            asm volatile("global_load_dwordx4 %0, %1, off" : "=v"(xb.v[4*j+3]) : "v"(p3));
        }
    };
    // stage double-tile d into wave-private LDS buffer `buf` (8 x 1KB, vmcnt)
    auto stageW2 = [&](int d, int buf) {
        _Float16* dstb = myLds + buf * 4096;
        #pragma unroll
        for (int q = 0; q < 8; ++q)
            gll16(pW + (size_t)(2 * d) * 2048 + q * 512, dstb + q * 512);
    };

    f32x4 acc[2][4] = {};
    XB2 x0, x1;

    // prologue issue order: W2(0), X2(0), W2(1), X2(1)  (32 outstanding)
    stageW2(0, 0); xload2(0, x0);
    stageW2(1, 1); xload2(1, x1);

#define GSTEP2(I, XC, WAITN)                                                   \
    {                                                                          \
        asm volatile("s_waitcnt vmcnt(" #WAITN ")" ::: "memory");              \
        __builtin_amdgcn_sched_barrier(0);                                     \
        const _Float16* rb = myLds + ((I) & 1) * 4096;                         \
        f16x8 WC[8];                                                           \
        _Pragma("unroll")                                                      \
        for (int q = 0; q < 8; ++q)                                            \
            WC[q] = *(const f16x8*)(rb + q * 512 + lane * 8);                  \
        f16x8 ah0, al0, ah1, al1, ch0, cl0, ch1, cl1;                          \
        split8h(XC.v[0], XC.v[1], ah0, al0);                                   \
        split8h(XC.v[2], XC.v[3], ah1, al1);                                   \
        split8h(XC.v[4], XC.v[5], ch0, cl0);                                   \
        split8h(XC.v[6], XC.v[7], ch1, cl1);                                   \
        asm volatile("s_waitcnt lgkmcnt(0)" ::: "memory");                     \
        __builtin_amdgcn_sched_barrier(0);                                     \
        if constexpr ((I) + 2 < 7) { stageW2((I) + 2, (I) & 1);                \
                                     xload2((I) + 2, XC); }                    \
        __builtin_amdgcn_sched_barrier(0);                                     \
        _Pragma("unroll")                                                      \
        for (int nt = 0; nt < 4; ++nt) {                                       \
            acc[0][nt] = MFMA16F(ah0, WC[nt], acc[0][nt], 0, 0, 0);            \
            acc[0][nt] = MFMA16F(al0, WC[nt], acc[0][nt], 0, 0, 0);            \
            acc[1][nt] = MFMA16F(ah1, WC[nt], acc[1][nt], 0, 0, 0);            \
            acc[1][nt] = MFMA16F(al1, WC[nt], acc[1][nt], 0, 0, 0);            \
        }                                                                      \
        _Pragma("unroll")                                                      \
        for (int nt = 0; nt < 4; ++nt) {                                       \
            acc[0][nt] = MFMA16F(ch0, WC[4 + nt], acc[0][nt], 0, 0, 0);        \
            acc[0][nt] = MFMA16F(cl0, WC[4 + nt], acc[0][nt], 0, 0, 0);        \
            acc[1][nt] = MFMA16F(ch1, WC[4 + nt], acc[1][nt], 0, 0, 0);        \
            acc[1][nt] = MFMA16F(cl1, WC[4 + nt], acc[1][nt], 0, 0, 0);        \
        }                                                                      \
    }

    GSTEP2(0, x0, 16)
    GSTEP2(1, x1, 16)
    GSTEP2(2, x0, 16)
    GSTEP2(3, x1, 16)
    GSTEP2(4, x0, 16)
    GSTEP2(5, x1, 16)
    GSTEP2(6, x0, 0)
#undef GSTEP2

    // ldsW regions of different waves alias red[] -> sync BEFORE overwriting
    __syncthreads();

    // partials -> LDS (C-layout: row = mt*16 + g4*4 + j, col = nt*16 + l15)
    #pragma unroll
    for (int mt = 0; mt < 2; ++mt)
        #pragma unroll
        for (int nt = 0; nt < 4; ++nt)
            #pragma unroll
            for (int j = 0; j < 4; ++j)
                red[wid][mt * 16 + g4 * 4 + j][nt * 16 + l15] = acc[mt][nt][j];
    __syncthreads();

    // reduce 4 k-partials + b1 into red[0] (disjoint (rr,seg) slots: race-free)
    {
        const int rr  = tid >> 3;
        const int seg = tid & 7;
        f32x4 s0 = *(const f32x4*)(b1 + seg * 8);
        f32x4 s1 = *(const f32x4*)(b1 + seg * 8 + 4);
        #pragma unroll
        for (int p = 0; p < 4; ++p) {
            s0 += *(const f32x4*)&red[p][rr][seg * 8];
            s1 += *(const f32x4*)&red[p][rr][seg * 8 + 4];
        }
        *(f32x4*)&red[0][rr][seg * 8]     = s0;
        *(f32x4*)&red[0][rr][seg * 8 + 4] = s1;
    }
    __syncthreads();
    if (wid >= 2) return;                     // waves 2,3 done (no barriers below)

    // ---------------- phase 2: 20-step LIF recurrence, all in registers ------
    const int lrow = wid * 16 + l15;

    float c1[2][8], c1m1[2][8];
    #pragma unroll
    for (int kt = 0; kt < 2; ++kt) {
        f32x4 u0 = *(const f32x4*)&red[0][lrow][kt * 32 + kg];
        f32x4 u1 = *(const f32x4*)&red[0][lrow][kt * 32 + kg + 4];
        #pragma unroll
        for (int i = 0; i < 4; ++i) {
            c1[kt][i] = u0[i];     c1[kt][4 + i] = u1[i];
            c1m1[kt][i] = u0[i] - THRESH; c1m1[kt][4 + i] = u1[i] - THRESH;
        }
    }

    bf16x8 W2hf[2][2], W2lf[2][2];
    #pragma unroll
    for (int rt = 0; rt < 2; ++rt)
        #pragma unroll
        for (int kt = 0; kt < 2; ++kt) {
            const float* wp = W2 + (rt * 16 + l15) * 64 + kt * 32 + kg;
            split8(*(const f32x4*)wp, *(const f32x4*)(wp + 4), W2hf[rt][kt], W2lf[rt][kt]);
        }

    float b2v[2][4], b2m1[2][4], w3a[2][4], w3b[2][4];
    #pragma unroll
    for (int nt = 0; nt < 2; ++nt)
        #pragma unroll
        for (int j = 0; j < 4; ++j) {
            const int o = nt * 16 + g4 * 4 + j;
            b2v[nt][j]  = b2[o];
            b2m1[nt][j] = b2[o] - THRESH;
            w3a[nt][j] = W3[o];
            w3b[nt][j] = W3[32 + o];
        }

    float m1[2][8] = {};
    float m2[2][4] = {};
    const int ns = nsp[0];
    for (int s = 0; s < ns; ++s) {
        bf16x8 mh[2], ml[2];
        #pragma unroll
        for (int kt = 0; kt < 2; ++kt)
            #pragma unroll
            for (int i = 0; i < 8; ++i) {
                float m = m1[kt][i];
                m = __builtin_fmaf(BETA, m, (m > THRESH) ? c1m1[kt][i] : c1[kt][i]);
                m1[kt][i] = m;
                short h, l; split_bf(m, h, l);
                mh[kt][i] = h; ml[kt][i] = l;
            }
        f32x4 a2[2][2] = {};
        #pragma unroll
        for (int rt = 0; rt < 2; ++rt)
            #pragma unroll
            for (int kt = 0; kt < 2; ++kt) {
                a2[rt][kt] = MFMA16(W2hf[rt][kt], mh[kt], a2[rt][kt], 0, 0, 0);
                a2[rt][kt] = MFMA16(W2lf[rt][kt], mh[kt], a2[rt][kt], 0, 0, 0);
                a2[rt][kt] = MFMA16(W2hf[rt][kt], ml[kt], a2[rt][kt], 0, 0, 0);
            }
        #pragma unroll
        for (int nt = 0; nt < 2; ++nt) {
            f32x4 c2 = a2[nt][0] + a2[nt][1];
            #pragma unroll
            for (int j = 0; j < 4; ++j) {
                float m = m2[nt][j];
                m2[nt][j] = __builtin_fmaf(
                    BETA, m, c2[j] + ((m > THRESH) ? b2m1[nt][j] : b2v[nt][j]));
            }
        }
    }

    float p0 = 0.f, p1 = 0.f;
    #pragma unroll
    for (int nt = 0; nt < 2; ++nt)
        #pragma unroll
        for (int j = 0; j < 4; ++j) {
            p0 = __builtin_fmaf(m2[nt][j], w3a[nt][j], p0);
            p1 = __builtin_fmaf(m2[nt][j], w3b[nt][j], p1);
        }
    p0 += __shfl_xor(p0, 16); p0 += __shfl_xor(p0, 32);
    p1 += __shfl_xor(p1, 16); p1 += __shfl_xor(p1, 32);
    if (lane < 16) {
        const size_t row = rowBase + lrow;
        out[row * 2 + 0] = p0 + b3[0];
        out[row * 2 + 1] = p1 + b3[1];
    }
}

extern "C" void kernel_launch(void* const* d_in, const int* in_sizes, int n_in,
                              void* d_out, int out_size, void* d_ws, size_t ws_size,
                              hipStream_t stream) {
    const float* x  = (const float*)d_in[0];
    const float* W1 = (const float*)d_in[1];
    const float* b1 = (const float*)d_in[2];
    const float* W2 = (const float*)d_in[3];
    const float* b2 = (const float*)d_in[4];
    const float* W3 = (const float*)d_in[5];
    const float* b3 = (const float*)d_in[6];
    const int*   ns = (const int*)d_in[7];
    float* o = (float*)d_out;

    const int B = in_sizes[0] / KDIM;              // 16384
    _Float16* WT = (_Float16*)d_ws;                // [56][2048] fp16 (224 KB)

    w1_relayout<<<NKT2, 256, 0, stream>>>(W1, WT);
    snn_fused<<<B / 32, 256, 0, stream>>>(x, WT, b1, W2, b2, W3, b3, ns, o);
}

// Round 21
// 40.584 us; speedup vs baseline: 1.0124x; 1.0108x over previous
//
#include <hip/hip_runtime.h>
#include <hip/hip_bf16.h>

typedef float f32x4 __attribute__((ext_vector_type(4)));
typedef short bf16x8 __attribute__((ext_vector_type(8)));
typedef _Float16 f16x8 __attribute__((ext_vector_type(8)));

#define MFMA16  __builtin_amdgcn_mfma_f32_16x16x32_bf16
#define MFMA16F __builtin_amdgcn_mfma_f32_16x16x32_f16

static constexpr int KDIM = 1700;
static constexpr int NKT2 = 56;         // padded k-tiles: 54 real (53 ragged) + 2 zero
static constexpr float BETA = 0.9f;
static constexpr float THRESH = 1.0f;

// fp32 -> bf16 hi + bf16 lo (residual) — used in the recurrence (unchanged)
__device__ __forceinline__ void split_bf(float f, short& hi, short& lo) {
    __hip_bfloat16 h = __float2bfloat16(f);
    float r = f - __bfloat162float(h);          // exact in fp32
    __hip_bfloat16 l = __float2bfloat16(r);
    hi = (short)__builtin_bit_cast(unsigned short, h);
    lo = (short)__builtin_bit_cast(unsigned short, l);
}

__device__ __forceinline__ void split8(f32x4 a, f32x4 b, bf16x8& hi, bf16x8& lo) {
    #pragma unroll
    for (int i = 0; i < 4; ++i) { short h, l; split_bf(a[i], h, l); hi[i] = h; lo[i] = l; }
    #pragma unroll
    for (int i = 0; i < 4; ++i) { short h, l; split_bf(b[i], h, l); hi[4 + i] = h; lo[4 + i] = l; }
}

// fp32 -> fp16 hi + fp16 lo (residual): x representation error ~2^-22 relative
__device__ __forceinline__ void split8h(f32x4 a, f32x4 b, f16x8& hi, f16x8& lo) {
    #pragma unroll
    for (int i = 0; i < 4; ++i) {
        _Float16 h = (_Float16)a[i];
        hi[i] = h; lo[i] = (_Float16)(a[i] - (float)h);
    }
    #pragma unroll
    for (int i = 0; i < 4; ++i) {
        _Float16 h = (_Float16)b[i];
        hi[4 + i] = h; lo[4 + i] = (_Float16)(b[i] - (float)h);
    }
}

// W1 [64][1700] f32 -> ONE fp16 plane in MFMA-B-fragment order, 56 k-tiles
// (k >= 1700 zero-padded).
__global__ void w1_relayout(const float* __restrict__ W1, _Float16* __restrict__ WT) {
    const int g    = blockIdx.x * 256 + threadIdx.x;   // 0 .. 56*256-1
    const int kt   = g >> 8;
    const int nt   = (g >> 6) & 3;
    const int lane = g & 63;
    const int n    = nt * 16 + (lane & 15);
    const int kb   = kt * 32 + (lane >> 4) * 8;
    f16x8 v;
    #pragma unroll
    for (int i = 0; i < 8; ++i) {
        const int k = kb + i;
        v[i] = (k < KDIM) ? (_Float16)W1[n * KDIM + k] : (_Float16)0.f;
    }
    *(f16x8*)(WT + (size_t)g * 8) = v;
}

__device__ __forceinline__ void gll16(const void* src, const void* lds_dst) {
    __builtin_amdgcn_global_load_lds(
        (const __attribute__((address_space(1))) unsigned int*)src,
        (__attribute__((address_space(3))) unsigned int*)lds_dst, 16, 0, 0);
}

// ---------------- fused kernel: cur1 GEMM (64 rows/block) + LIF --------------
// 512 thr = 8 waves = K-split-8 (7 tiles/wave), each wave covers ALL 64 rows.
// Grid = B/64 = 256 = 1 block/CU -> per-CU W instructions AND W traffic halve
// vs r18 (the only lever that has moved the number: r18/r12). Pipeline =
// r18's validated form: W gll16 double-buffer + x 2-deep asm ring.
// Ledger: prologue W0[4],x0[8],W1[4],x1[8] = 24 outstanding; steps 0-5 wait
// vmcnt(12) = drain exactly W(I)+x(I); step 6 waits 0. r14 hazard invariant:
// buf I&1 ds_reads + lgkmcnt(0) precede its restage by W(I+2).
__global__ __launch_bounds__(512, 1) void snn_fused(
    const float* __restrict__ x, const _Float16* __restrict__ WT,
    const float* __restrict__ b1, const float* __restrict__ W2,
    const float* __restrict__ b2, const float* __restrict__ W3,
    const float* __restrict__ b3, const int* __restrict__ nsp,
    float* __restrict__ out)
{
    __shared__ __align__(16) char smemraw[69632];   // W 64KB loop / red[4][64][68]
    _Float16* ldsW = (_Float16*)smemraw;
    float (*red)[64][68] = (float (*)[64][68])smemraw;

    const int tid = threadIdx.x;
    const int wid = tid >> 6;                  // 0..7 = K-eighth
    const int lane = tid & 63;
    const int l15 = lane & 15;
    const int g4  = lane >> 4;
    const int kg  = g4 * 8;
    const int rowBase = blockIdx.x * 64;
    const int tb  = wid * 7;                   // this wave's first k-tile

    const _Float16* pW = WT + (size_t)tb * 2048 + lane * 8;   // per-lane W src
    _Float16* myLds = ldsW + wid * 4096;       // 8KB/wave (2 x 4KB bufs)

    struct XB { f32x4 v[8]; };                 // 4 row-groups x 2 k-halves
    // x fragment load, 8 coalesced-fragment dwordx4 per tile (64 rows).
    // asm-pinned issue; consumption guarded by counted vmcnt. Clamp k>=1700.
    auto xload = [&](int t, XB& xb) {
        const int k1 = t * 32 + kg;
        const int kc1 = (k1 <= 1696) ? k1 : 1664;
        const int kc2 = (k1 + 4 <= 1696) ? k1 + 4 : 1664;
        #pragma unroll
        for (int rg = 0; rg < 4; ++rg) {
            const float* xr = x + (size_t)(rowBase + rg * 16 + l15) * KDIM;
            const float* p0 = xr + kc1;
            const float* p1 = xr + kc2;
            asm volatile("global_load_dwordx4 %0, %1, off" : "=v"(xb.v[2*rg])   : "v"(p0));
            asm volatile("global_load_dwordx4 %0, %1, off" : "=v"(xb.v[2*rg+1]) : "v"(p1));
        }
    };
    // stage tile (tb+i) into wave-private LDS buffer `buf` (4 x 1KB, vmcnt)
    auto stageW = [&](int i, int buf) {
        _Float16* dstb = myLds + buf * 2048;
        #pragma unroll
        for (int q = 0; q < 4; ++q)
            gll16(pW + (size_t)i * 2048 + q * 512, dstb + q * 512);
    };

    f32x4 acc[4][4] = {};
    XB x0, x1;

    // prologue issue order: W0, x0, W1, x1  (24 outstanding)
    stageW(0, 0); xload(tb + 0, x0);
    stageW(1, 1); xload(tb + 1, x1);

#define GSTEP(I, XC, WAITN)                                                    \
    {                                                                          \
        asm volatile("s_waitcnt vmcnt(" #WAITN ")" ::: "memory");              \
        __builtin_amdgcn_sched_barrier(0);                                     \
        const _Float16* rb = myLds + ((I) & 1) * 2048;                         \
        f16x8 WC[4];                                                           \
        _Pragma("unroll")                                                      \
        for (int q = 0; q < 4; ++q)                                            \
            WC[q] = *(const f16x8*)(rb + q * 512 + lane * 8);                  \
        f16x8 ah[4], al[4];                                                    \
        _Pragma("unroll")                                                      \
        for (int rg = 0; rg < 4; ++rg)                                         \
            split8h(XC.v[2*rg], XC.v[2*rg+1], ah[rg], al[rg]);                 \
        asm volatile("s_waitcnt lgkmcnt(0)" ::: "memory");                     \
        __builtin_amdgcn_sched_barrier(0);                                     \
        if constexpr ((I) + 2 < 7) { stageW((I) + 2, (I) & 1);                 \
                                     xload(tb + (I) + 2, XC); }                \
        __builtin_amdgcn_sched_barrier(0);                                     \
        _Pragma("unroll")                                                      \
        for (int mt = 0; mt < 4; ++mt)                                         \
            _Pragma("unroll")                                                  \
            for (int nt = 0; nt < 4; ++nt) {                                   \
                acc[mt][nt] = MFMA16F(ah[mt], WC[nt], acc[mt][nt], 0, 0, 0);   \
                acc[mt][nt] = MFMA16F(al[mt], WC[nt], acc[mt][nt], 0, 0, 0);   \
            }                                                                  \
    }

    GSTEP(0, x0, 12)
    GSTEP(1, x1, 12)
    GSTEP(2, x0, 12)
    GSTEP(3, x1, 12)
    GSTEP(4, x0, 12)
    GSTEP(5, x1, 12)
    GSTEP(6, x0, 0)
#undef GSTEP

    // ---- 8-partial reduction in 70KB LDS (W region dead after barrier) ------
    __syncthreads();
    if (wid >= 4) {                            // waves 4-7 dump partials
        #pragma unroll
        for (int mt = 0; mt < 4; ++mt)
            #pragma unroll
            for (int nt = 0; nt < 4; ++nt)
                #pragma unroll
                for (int j = 0; j < 4; ++j)
                    red[wid - 4][mt * 16 + g4 * 4 + j][nt * 16 + l15] = acc[mt][nt][j];
    }
    __syncthreads();
    if (wid < 4) {                             // fold partner (wid+4), write back
        #pragma unroll
        for (int mt = 0; mt < 4; ++mt)
            #pragma unroll
            for (int nt = 0; nt < 4; ++nt)
                #pragma unroll
                for (int j = 0; j < 4; ++j) {
                    float v = acc[mt][nt][j]
                            + red[wid][mt * 16 + g4 * 4 + j][nt * 16 + l15];
                    red[wid][mt * 16 + g4 * 4 + j][nt * 16 + l15] = v;
                }
    }
    __syncthreads();
    // final fold of 4 + b1 -> red[0]; 512 tasks = 64 rows x 8 segs, disjoint
    {
        const int rr  = tid >> 3;
        const int seg = tid & 7;
        f32x4 s0 = *(const f32x4*)(b1 + seg * 8);
        f32x4 s1 = *(const f32x4*)(b1 + seg * 8 + 4);
        #pragma unroll
        for (int p = 0; p < 4; ++p) {
            s0 += *(const f32x4*)&red[p][rr][seg * 8];
            s1 += *(const f32x4*)&red[p][rr][seg * 8 + 4];
        }
        *(f32x4*)&red[0][rr][seg * 8]     = s0;
        *(f32x4*)&red[0][rr][seg * 8 + 4] = s1;
    }
    __syncthreads();
    if (wid >= 4) return;                      // waves 4-7 done (no barriers below)

    // ---------------- phase 2: 20-step LIF recurrence, all in registers ------
    const int lrow = wid * 16 + l15;           // waves 0-3 cover rows 0..63

    float c1[2][8], c1m1[2][8];
    #pragma unroll
    for (int kt = 0; kt < 2; ++kt) {
        f32x4 u0 = *(const f32x4*)&red[0][lrow][kt * 32 + kg];
        f32x4 u1 = *(const f32x4*)&red[0][lrow][kt * 32 + kg + 4];
        #pragma unroll
        for (int i = 0; i < 4; ++i) {
            c1[kt][i] = u0[i];     c1[kt][4 + i] = u1[i];
            c1m1[kt][i] = u0[i] - THRESH; c1m1[kt][4 + i] = u1[i] - THRESH;
        }
    }

    bf16x8 W2hf[2][2], W2lf[2][2];
    #pragma unroll
    for (int rt = 0; rt < 2; ++rt)
        #pragma unroll
        for (int kt = 0; kt < 2; ++kt) {
            const float* wp = W2 + (rt * 16 + l15) * 64 + kt * 32 + kg;
            split8(*(const f32x4*)wp, *(const f32x4*)(wp + 4), W2hf[rt][kt], W2lf[rt][kt]);
        }

    float b2v[2][4], b2m1[2][4], w3a[2][4], w3b[2][4];
    #pragma unroll
    for (int nt = 0; nt < 2; ++nt)
        #pragma unroll
        for (int j = 0; j < 4; ++j) {
            const int o = nt * 16 + g4 * 4 + j;
            b2v[nt][j]  = b2[o];
            b2m1[nt][j] = b2[o] - THRESH;
            w3a[nt][j] = W3[o];
            w3b[nt][j] = W3[32 + o];
        }

    float m1[2][8] = {};
    float m2[2][4] = {};
    const int ns = nsp[0];
    for (int s = 0; s < ns; ++s) {
        bf16x8 mh[2], ml[2];
        #pragma unroll
        for (int kt = 0; kt < 2; ++kt)
            #pragma unroll
            for (int i = 0; i < 8; ++i) {
                float m = m1[kt][i];
                m = __builtin_fmaf(BETA, m, (m > THRESH) ? c1m1[kt][i] : c1[kt][i]);
                m1[kt][i] = m;
                short h, l; split_bf(m, h, l);
                mh[kt][i] = h; ml[kt][i] = l;
            }
        f32x4 a2[2][2] = {};
        #pragma unroll
        for (int rt = 0; rt < 2; ++rt)
            #pragma unroll
            for (int kt = 0; kt < 2; ++kt) {
                a2[rt][kt] = MFMA16(W2hf[rt][kt], mh[kt], a2[rt][kt], 0, 0, 0);
                a2[rt][kt] = MFMA16(W2lf[rt][kt], mh[kt], a2[rt][kt], 0, 0, 0);
                a2[rt][kt] = MFMA16(W2hf[rt][kt], ml[kt], a2[rt][kt], 0, 0, 0);
            }
        #pragma unroll
        for (int nt = 0; nt < 2; ++nt) {
            f32x4 c2 = a2[nt][0] + a2[nt][1];
            #pragma unroll
            for (int j = 0; j < 4; ++j) {
                float m = m2[nt][j];
                m2[nt][j] = __builtin_fmaf(
                    BETA, m, c2[j] + ((m > THRESH) ? b2m1[nt][j] : b2v[nt][j]));
            }
        }
    }

    float p0 = 0.f, p1 = 0.f;
    #pragma unroll
    for (int nt = 0; nt < 2; ++nt)
        #pragma unroll
        for (int j = 0; j < 4; ++j) {
            p0 = __builtin_fmaf(m2[nt][j], w3a[nt][j], p0);
            p1 = __builtin_fmaf(m2[nt][j], w3b[nt][j], p1);
        }
    p0 += __shfl_xor(p0, 16); p0 += __shfl_xor(p0, 32);
    p1 += __shfl_xor(p1, 16); p1 += __shfl_xor(p1, 32);
    if (lane < 16) {
        const size_t row = rowBase + lrow;
        out[row * 2 + 0] = p0 + b3[0];
        out[row * 2 + 1] = p1 + b3[1];
    }
}

extern "C" void kernel_launch(void* const* d_in, const int* in_sizes, int n_in,
                              void* d_out, int out_size, void* d_ws, size_t ws_size,
                              hipStream_t stream) {
    const float* x  = (const float*)d_in[0];
    const float* W1 = (const float*)d_in[1];
    const float* b1 = (const float*)d_in[2];
    const float* W2 = (const float*)d_in[3];
    const float* b2 = (const float*)d_in[4];
    const float* W3 = (const float*)d_in[5];
    const float* b3 = (const float*)d_in[6];
    const int*   ns = (const int*)d_in[7];
    float* o = (float*)d_out;

    const int B = in_sizes[0] / KDIM;              // 16384
    _Float16* WT = (_Float16*)d_ws;                // [56][2048] fp16 (224 KB)

    w1_relayout<<<NKT2, 256, 0, stream>>>(W1, WT);
    snn_fused<<<B / 64, 512, 0, stream>>>(x, WT, b1, W2, b2, W3, b3, ns, o);
}

// Round 22
// 38.611 us; speedup vs baseline: 1.0642x; 1.0511x over previous
//
#include <hip/hip_runtime.h>
#include <hip/hip_bf16.h>

typedef float f32x4 __attribute__((ext_vector_type(4)));
typedef _Float16 f16x8 __attribute__((ext_vector_type(8)));

#define MFMA16F __builtin_amdgcn_mfma_f32_16x16x32_f16

static constexpr int KDIM = 1700;
static constexpr int NKT2 = 56;         // padded k-tiles: 54 real (53 ragged) + 2 zero
static constexpr float BETA = 0.9f;
static constexpr float THRESH = 1.0f;

// fp32 -> fp16 hi + fp16 lo (residual): representation error ~2^-22 relative
__device__ __forceinline__ void split8h(f32x4 a, f32x4 b, f16x8& hi, f16x8& lo) {
    #pragma unroll
    for (int i = 0; i < 4; ++i) {
        _Float16 h = (_Float16)a[i];
        hi[i] = h; lo[i] = (_Float16)(a[i] - (float)h);
    }
    #pragma unroll
    for (int i = 0; i < 4; ++i) {
        _Float16 h = (_Float16)b[i];
        hi[4 + i] = h; lo[4 + i] = (_Float16)(b[i] - (float)h);
    }
}

// W1 [64][1700] f32 -> ONE fp16 plane in MFMA-B-fragment order, 56 k-tiles
// (k >= 1700 zero-padded).
__global__ void w1_relayout(const float* __restrict__ W1, _Float16* __restrict__ WT) {
    const int g    = blockIdx.x * 256 + threadIdx.x;   // 0 .. 56*256-1
    const int kt   = g >> 8;
    const int nt   = (g >> 6) & 3;
    const int lane = g & 63;
    const int n    = nt * 16 + (lane & 15);
    const int kb   = kt * 32 + (lane >> 4) * 8;
    f16x8 v;
    #pragma unroll
    for (int i = 0; i < 8; ++i) {
        const int k = kb + i;
        v[i] = (k < KDIM) ? (_Float16)W1[n * KDIM + k] : (_Float16)0.f;
    }
    *(f16x8*)(WT + (size_t)g * 8) = v;
}

__device__ __forceinline__ void gll16(const void* src, const void* lds_dst) {
    __builtin_amdgcn_global_load_lds(
        (const __attribute__((address_space(1))) unsigned int*)src,
        (__attribute__((address_space(3))) unsigned int*)lds_dst, 16, 0, 0);
}

// ---------------- fused kernel: cur1 GEMM (64 rows/block) + LIF --------------
// GEMM phase = r21 verbatim (verified 40.58us): 512 thr = 8 waves = K-split-8,
// W gll16 double-buffer + x 2-deep asm ring, counted vmcnt.
// Phase 2 trimmed (this round): W2 as fp16 hi+lo (constant split), mem1 as
// SINGLE fp16 (1 cvt/elem vs 4-op bf16 split) -> 8 MFMA/step (was 12),
// ~120 VALU/step (was ~190).
__global__ __launch_bounds__(512, 1) void snn_fused(
    const float* __restrict__ x, const _Float16* __restrict__ WT,
    const float* __restrict__ b1, const float* __restrict__ W2,
    const float* __restrict__ b2, const float* __restrict__ W3,
    const float* __restrict__ b3, const int* __restrict__ nsp,
    float* __restrict__ out)
{
    __shared__ __align__(16) char smemraw[69632];   // W 64KB loop / red[4][64][68]
    _Float16* ldsW = (_Float16*)smemraw;
    float (*red)[64][68] = (float (*)[64][68])smemraw;

    const int tid = threadIdx.x;
    const int wid = tid >> 6;                  // 0..7 = K-eighth
    const int lane = tid & 63;
    const int l15 = lane & 15;
    const int g4  = lane >> 4;
    const int kg  = g4 * 8;
    const int rowBase = blockIdx.x * 64;
    const int tb  = wid * 7;                   // this wave's first k-tile

    const _Float16* pW = WT + (size_t)tb * 2048 + lane * 8;   // per-lane W src
    _Float16* myLds = ldsW + wid * 4096;       // 8KB/wave (2 x 4KB bufs)

    struct XB { f32x4 v[8]; };                 // 4 row-groups x 2 k-halves
    auto xload = [&](int t, XB& xb) {
        const int k1 = t * 32 + kg;
        const int kc1 = (k1 <= 1696) ? k1 : 1664;
        const int kc2 = (k1 + 4 <= 1696) ? k1 + 4 : 1664;
        #pragma unroll
        for (int rg = 0; rg < 4; ++rg) {
            const float* xr = x + (size_t)(rowBase + rg * 16 + l15) * KDIM;
            const float* p0 = xr + kc1;
            const float* p1 = xr + kc2;
            asm volatile("global_load_dwordx4 %0, %1, off" : "=v"(xb.v[2*rg])   : "v"(p0));
            asm volatile("global_load_dwordx4 %0, %1, off" : "=v"(xb.v[2*rg+1]) : "v"(p1));
        }
    };
    auto stageW = [&](int i, int buf) {
        _Float16* dstb = myLds + buf * 2048;
        #pragma unroll
        for (int q = 0; q < 4; ++q)
            gll16(pW + (size_t)i * 2048 + q * 512, dstb + q * 512);
    };

    f32x4 acc[4][4] = {};
    XB x0, x1;

    // prologue issue order: W0, x0, W1, x1  (24 outstanding)
    stageW(0, 0); xload(tb + 0, x0);
    stageW(1, 1); xload(tb + 1, x1);

#define GSTEP(I, XC, WAITN)                                                    \
    {                                                                          \
        asm volatile("s_waitcnt vmcnt(" #WAITN ")" ::: "memory");              \
        __builtin_amdgcn_sched_barrier(0);                                     \
        const _Float16* rb = myLds + ((I) & 1) * 2048;                         \
        f16x8 WC[4];                                                           \
        _Pragma("unroll")                                                      \
        for (int q = 0; q < 4; ++q)                                            \
            WC[q] = *(const f16x8*)(rb + q * 512 + lane * 8);                  \
        f16x8 ah[4], al[4];                                                    \
        _Pragma("unroll")                                                      \
        for (int rg = 0; rg < 4; ++rg)                                         \
            split8h(XC.v[2*rg], XC.v[2*rg+1], ah[rg], al[rg]);                 \
        asm volatile("s_waitcnt lgkmcnt(0)" ::: "memory");                     \
        __builtin_amdgcn_sched_barrier(0);                                     \
        if constexpr ((I) + 2 < 7) { stageW((I) + 2, (I) & 1);                 \
                                     xload(tb + (I) + 2, XC); }                \
        __builtin_amdgcn_sched_barrier(0);                                     \
        _Pragma("unroll")                                                      \
        for (int mt = 0; mt < 4; ++mt)                                         \
            _Pragma("unroll")                                                  \
            for (int nt = 0; nt < 4; ++nt) {                                   \
                acc[mt][nt] = MFMA16F(ah[mt], WC[nt], acc[mt][nt], 0, 0, 0);   \
                acc[mt][nt] = MFMA16F(al[mt], WC[nt], acc[mt][nt], 0, 0, 0);   \
            }                                                                  \
    }

    GSTEP(0, x0, 12)
    GSTEP(1, x1, 12)
    GSTEP(2, x0, 12)
    GSTEP(3, x1, 12)
    GSTEP(4, x0, 12)
    GSTEP(5, x1, 12)
    GSTEP(6, x0, 0)
#undef GSTEP

    // ---- 8-partial reduction in 70KB LDS (W region dead after barrier) ------
    __syncthreads();
    if (wid >= 4) {                            // waves 4-7 dump partials
        #pragma unroll
        for (int mt = 0; mt < 4; ++mt)
            #pragma unroll
            for (int nt = 0; nt < 4; ++nt)
                #pragma unroll
                for (int j = 0; j < 4; ++j)
                    red[wid - 4][mt * 16 + g4 * 4 + j][nt * 16 + l15] = acc[mt][nt][j];
    }
    __syncthreads();
    if (wid < 4) {                             // fold partner (wid+4), write back
        #pragma unroll
        for (int mt = 0; mt < 4; ++mt)
            #pragma unroll
            for (int nt = 0; nt < 4; ++nt)
                #pragma unroll
                for (int j = 0; j < 4; ++j) {
                    float v = acc[mt][nt][j]
                            + red[wid][mt * 16 + g4 * 4 + j][nt * 16 + l15];
                    red[wid][mt * 16 + g4 * 4 + j][nt * 16 + l15] = v;
                }
    }
    __syncthreads();
    // final fold of 4 + b1 -> red[0]; 512 tasks = 64 rows x 8 segs, disjoint
    {
        const int rr  = tid >> 3;
        const int seg = tid & 7;
        f32x4 s0 = *(const f32x4*)(b1 + seg * 8);
        f32x4 s1 = *(const f32x4*)(b1 + seg * 8 + 4);
        #pragma unroll
        for (int p = 0; p < 4; ++p) {
            s0 += *(const f32x4*)&red[p][rr][seg * 8];
            s1 += *(const f32x4*)&red[p][rr][seg * 8 + 4];
        }
        *(f32x4*)&red[0][rr][seg * 8]     = s0;
        *(f32x4*)&red[0][rr][seg * 8 + 4] = s1;
    }
    __syncthreads();
    if (wid >= 4) return;                      // waves 4-7 done (no barriers below)

    // ---------------- phase 2: 20-step LIF recurrence, all in registers ------
    const int lrow = wid * 16 + l15;           // waves 0-3 cover rows 0..63

    float c1[2][8], c1m1[2][8];
    #pragma unroll
    for (int kt = 0; kt < 2; ++kt) {
        f32x4 u0 = *(const f32x4*)&red[0][lrow][kt * 32 + kg];
        f32x4 u1 = *(const f32x4*)&red[0][lrow][kt * 32 + kg + 4];
        #pragma unroll
        for (int i = 0; i < 4; ++i) {
            c1[kt][i] = u0[i];     c1[kt][4 + i] = u1[i];
            c1m1[kt][i] = u0[i] - THRESH; c1m1[kt][4 + i] = u1[i] - THRESH;
        }
    }

    // W2 as fp16 hi+lo MFMA A-operand: lane holds W2[rt*16+l15][kt*32+kg+i]
    f16x8 W2hf[2][2], W2lf[2][2];
    #pragma unroll
    for (int rt = 0; rt < 2; ++rt)
        #pragma unroll
        for (int kt = 0; kt < 2; ++kt) {
            const float* wp = W2 + (rt * 16 + l15) * 64 + kt * 32 + kg;
            split8h(*(const f32x4*)wp, *(const f32x4*)(wp + 4), W2hf[rt][kt], W2lf[rt][kt]);
        }

    float b2v[2][4], b2m1[2][4], w3a[2][4], w3b[2][4];
    #pragma unroll
    for (int nt = 0; nt < 2; ++nt)
        #pragma unroll
        for (int j = 0; j < 4; ++j) {
            const int o = nt * 16 + g4 * 4 + j;
            b2v[nt][j]  = b2[o];
            b2m1[nt][j] = b2[o] - THRESH;
            w3a[nt][j] = W3[o];
            w3b[nt][j] = W3[32 + o];
        }

    float m1[2][8] = {};
    float m2[2][4] = {};
    const int ns = nsp[0];
    for (int s = 0; s < ns; ++s) {
        // mem1 update + SINGLE fp16 quantization (1 cvt/elem)
        f16x8 mh[2];
        #pragma unroll
        for (int kt = 0; kt < 2; ++kt)
            #pragma unroll
            for (int i = 0; i < 8; ++i) {
                float m = m1[kt][i];
                m = __builtin_fmaf(BETA, m, (m > THRESH) ? c1m1[kt][i] : c1[kt][i]);
                m1[kt][i] = m;
                mh[kt][i] = (_Float16)m;
            }
        // cur2^T = W2 @ mem1^T : 2-term (W2 hi/lo) x 1-term mem1 = 8 MFMA
        f32x4 a2[2][2] = {};
        #pragma unroll
        for (int rt = 0; rt < 2; ++rt)
            #pragma unroll
            for (int kt = 0; kt < 2; ++kt) {
                a2[rt][kt] = MFMA16F(W2hf[rt][kt], mh[kt], a2[rt][kt], 0, 0, 0);
                a2[rt][kt] = MFMA16F(W2lf[rt][kt], mh[kt], a2[rt][kt], 0, 0, 0);
            }
        #pragma unroll
        for (int nt = 0; nt < 2; ++nt) {
            f32x4 c2 = a2[nt][0] + a2[nt][1];
            #pragma unroll
            for (int j = 0; j < 4; ++j) {
                float m = m2[nt][j];
                m2[nt][j] = __builtin_fmaf(
                    BETA, m, c2[j] + ((m > THRESH) ? b2m1[nt][j] : b2v[nt][j]));
            }
        }
    }

    float p0 = 0.f, p1 = 0.f;
    #pragma unroll
    for (int nt = 0; nt < 2; ++nt)
        #pragma unroll
        for (int j = 0; j < 4; ++j) {
            p0 = __builtin_fmaf(m2[nt][j], w3a[nt][j], p0);
            p1 = __builtin_fmaf(m2[nt][j], w3b[nt][j], p1);
        }
    p0 += __shfl_xor(p0, 16); p0 += __shfl_xor(p0, 32);
    p1 += __shfl_xor(p1, 16); p1 += __shfl_xor(p1, 32);
    if (lane < 16) {
        const size_t row = rowBase + lrow;
        out[row * 2 + 0] = p0 + b3[0];
        out[row * 2 + 1] = p1 + b3[1];
    }
}

extern "C" void kernel_launch(void* const* d_in, const int* in_sizes, int n_in,
                              void* d_out, int out_size, void* d_ws, size_t ws_size,
                              hipStream_t stream) {
    const float* x  = (const float*)d_in[0];
    const float* W1 = (const float*)d_in[1];
    const float* b1 = (const float*)d_in[2];
    const float* W2 = (const float*)d_in[3];
    const float* b2 = (const float*)d_in[4];
    const float* W3 = (const float*)d_in[5];
    const float* b3 = (const float*)d_in[6];
    const int*   ns = (const int*)d_in[7];
    float* o = (float*)d_out;

    const int B = in_sizes[0] / KDIM;              // 16384
    _Float16* WT = (_Float16*)d_ws;                // [56][2048] fp16 (224 KB)

    w1_relayout<<<NKT2, 256, 0, stream>>>(W1, WT);
    snn_fused<<<B / 64, 512, 0, stream>>>(x, WT, b1, W2, b2, W3, b3, ns, o);
}

// Round 23
// 37.062 us; speedup vs baseline: 1.1087x; 1.0418x over previous
//
#include <hip/hip_runtime.h>
#include <hip/hip_bf16.h>

typedef float f32x4 __attribute__((ext_vector_type(4)));
typedef _Float16 f16x8 __attribute__((ext_vector_type(8)));

#define MFMA16F __builtin_amdgcn_mfma_f32_16x16x32_f16

static constexpr int KDIM = 1700;
static constexpr int NKT2 = 56;         // padded k-tiles: 54 real (53 ragged) + 2 zero
static constexpr float BETA = 0.9f;
static constexpr float THRESH = 1.0f;

// fp32 -> fp16 hi + fp16 lo (residual) — used for W2 in the recurrence
__device__ __forceinline__ void split8h(f32x4 a, f32x4 b, f16x8& hi, f16x8& lo) {
    #pragma unroll
    for (int i = 0; i < 4; ++i) {
        _Float16 h = (_Float16)a[i];
        hi[i] = h; lo[i] = (_Float16)(a[i] - (float)h);
    }
    #pragma unroll
    for (int i = 0; i < 4; ++i) {
        _Float16 h = (_Float16)b[i];
        hi[4 + i] = h; lo[4 + i] = (_Float16)(b[i] - (float)h);
    }
}

// fp32x8 -> fp16x8 single-term conversion (1 cvt/elem)
__device__ __forceinline__ f16x8 cvt8h(f32x4 a, f32x4 b) {
    f16x8 r;
    #pragma unroll
    for (int i = 0; i < 4; ++i) { r[i] = (_Float16)a[i]; r[4 + i] = (_Float16)b[i]; }
    return r;
}

// W1 [64][1700] f32 -> ONE fp16 plane in MFMA-B-fragment order, 56 k-tiles
// (k >= 1700 zero-padded).
__global__ void w1_relayout(const float* __restrict__ W1, _Float16* __restrict__ WT) {
    const int g    = blockIdx.x * 256 + threadIdx.x;   // 0 .. 56*256-1
    const int kt   = g >> 8;
    const int nt   = (g >> 6) & 3;
    const int lane = g & 63;
    const int n    = nt * 16 + (lane & 15);
    const int kb   = kt * 32 + (lane >> 4) * 8;
    f16x8 v;
    #pragma unroll
    for (int i = 0; i < 8; ++i) {
        const int k = kb + i;
        v[i] = (k < KDIM) ? (_Float16)W1[n * KDIM + k] : (_Float16)0.f;
    }
    *(f16x8*)(WT + (size_t)g * 8) = v;
}

__device__ __forceinline__ void gll16(const void* src, const void* lds_dst) {
    __builtin_amdgcn_global_load_lds(
        (const __attribute__((address_space(1))) unsigned int*)src,
        (__attribute__((address_space(3))) unsigned int*)lds_dst, 16, 0, 0);
}

// ---------------- fused kernel: cur1 GEMM (64 rows/block) + LIF --------------
// GEMM phase = r21/r22 structure with x trimmed to SINGLE fp16 (1 cvt/elem,
// 16 MFMA/step vs 32) — the compute-trim lever (r3/r18/r22 wins) applied to
// the last untrimmed arithmetic. cur1 noise 4e-4 -> ~5e-4 (still << 1.56 gate).
// Ledger: prologue W0[4],x0[8],W1[4],x1[8] = 24 outstanding; steps 0-5 wait
// vmcnt(12) = drain exactly W(I)+x(I); step 6 waits 0. r14 hazard invariant:
// buf I&1 ds_reads + lgkmcnt(0) precede its restage by W(I+2).
__global__ __launch_bounds__(512, 1) void snn_fused(
    const float* __restrict__ x, const _Float16* __restrict__ WT,
    const float* __restrict__ b1, const float* __restrict__ W2,
    const float* __restrict__ b2, const float* __restrict__ W3,
    const float* __restrict__ b3, const int* __restrict__ nsp,
    float* __restrict__ out)
{
    __shared__ __align__(16) char smemraw[69632];   // W 64KB loop / red[4][64][68]
    _Float16* ldsW = (_Float16*)smemraw;
    float (*red)[64][68] = (float (*)[64][68])smemraw;

    const int tid = threadIdx.x;
    const int wid = tid >> 6;                  // 0..7 = K-eighth
    const int lane = tid & 63;
    const int l15 = lane & 15;
    const int g4  = lane >> 4;
    const int kg  = g4 * 8;
    const int rowBase = blockIdx.x * 64;
    const int tb  = wid * 7;                   // this wave's first k-tile

    const _Float16* pW = WT + (size_t)tb * 2048 + lane * 8;   // per-lane W src
    _Float16* myLds = ldsW + wid * 4096;       // 8KB/wave (2 x 4KB bufs)

    struct XB { f32x4 v[8]; };                 // 4 row-groups x 2 k-halves
    auto xload = [&](int t, XB& xb) {
        const int k1 = t * 32 + kg;
        const int kc1 = (k1 <= 1696) ? k1 : 1664;
        const int kc2 = (k1 + 4 <= 1696) ? k1 + 4 : 1664;
        #pragma unroll
        for (int rg = 0; rg < 4; ++rg) {
            const float* xr = x + (size_t)(rowBase + rg * 16 + l15) * KDIM;
            const float* p0 = xr + kc1;
            const float* p1 = xr + kc2;
            asm volatile("global_load_dwordx4 %0, %1, off" : "=v"(xb.v[2*rg])   : "v"(p0));
            asm volatile("global_load_dwordx4 %0, %1, off" : "=v"(xb.v[2*rg+1]) : "v"(p1));
        }
    };
    auto stageW = [&](int i, int buf) {
        _Float16* dstb = myLds + buf * 2048;
        #pragma unroll
        for (int q = 0; q < 4; ++q)
            gll16(pW + (size_t)i * 2048 + q * 512, dstb + q * 512);
    };

    f32x4 acc[4][4] = {};
    XB x0, x1;

    // prologue issue order: W0, x0, W1, x1  (24 outstanding)
    stageW(0, 0); xload(tb + 0, x0);
    stageW(1, 1); xload(tb + 1, x1);

#define GSTEP(I, XC, WAITN)                                                    \
    {                                                                          \
        asm volatile("s_waitcnt vmcnt(" #WAITN ")" ::: "memory");              \
        __builtin_amdgcn_sched_barrier(0);                                     \
        const _Float16* rb = myLds + ((I) & 1) * 2048;                         \
        f16x8 WC[4];                                                           \
        _Pragma("unroll")                                                      \
        for (int q = 0; q < 4; ++q)                                            \
            WC[q] = *(const f16x8*)(rb + q * 512 + lane * 8);                  \
        f16x8 ah[4];                                                           \
        _Pragma("unroll")                                                      \
        for (int rg = 0; rg < 4; ++rg)                                         \
            ah[rg] = cvt8h(XC.v[2*rg], XC.v[2*rg+1]);                          \
        asm volatile("s_waitcnt lgkmcnt(0)" ::: "memory");                     \
        __builtin_amdgcn_sched_barrier(0);                                     \
        if constexpr ((I) + 2 < 7) { stageW((I) + 2, (I) & 1);                 \
                                     xload(tb + (I) + 2, XC); }                \
        __builtin_amdgcn_sched_barrier(0);                                     \
        _Pragma("unroll")                                                      \
        for (int mt = 0; mt < 4; ++mt)                                         \
            _Pragma("unroll")                                                  \
            for (int nt = 0; nt < 4; ++nt)                                     \
                acc[mt][nt] = MFMA16F(ah[mt], WC[nt], acc[mt][nt], 0, 0, 0);   \
    }

    GSTEP(0, x0, 12)
    GSTEP(1, x1, 12)
    GSTEP(2, x0, 12)
    GSTEP(3, x1, 12)
    GSTEP(4, x0, 12)
    GSTEP(5, x1, 12)
    GSTEP(6, x0, 0)
#undef GSTEP

    // ---- 8-partial reduction in 70KB LDS (W region dead after barrier) ------
    __syncthreads();
    if (wid >= 4) {                            // waves 4-7 dump partials
        #pragma unroll
        for (int mt = 0; mt < 4; ++mt)
            #pragma unroll
            for (int nt = 0; nt < 4; ++nt)
                #pragma unroll
                for (int j = 0; j < 4; ++j)
                    red[wid - 4][mt * 16 + g4 * 4 + j][nt * 16 + l15] = acc[mt][nt][j];
    }
    __syncthreads();
    if (wid < 4) {                             // fold partner (wid+4), write back
        #pragma unroll
        for (int mt = 0; mt < 4; ++mt)
            #pragma unroll
            for (int nt = 0; nt < 4; ++nt)
                #pragma unroll
                for (int j = 0; j < 4; ++j) {
                    float v = acc[mt][nt][j]
                            + red[wid][mt * 16 + g4 * 4 + j][nt * 16 + l15];
                    red[wid][mt * 16 + g4 * 4 + j][nt * 16 + l15] = v;
                }
    }
    __syncthreads();
    // final fold of 4 + b1 -> red[0]; 512 tasks = 64 rows x 8 segs, disjoint
    {
        const int rr  = tid >> 3;
        const int seg = tid & 7;
        f32x4 s0 = *(const f32x4*)(b1 + seg * 8);
        f32x4 s1 = *(const f32x4*)(b1 + seg * 8 + 4);
        #pragma unroll
        for (int p = 0; p < 4; ++p) {
            s0 += *(const f32x4*)&red[p][rr][seg * 8];
            s1 += *(const f32x4*)&red[p][rr][seg * 8 + 4];
        }
        *(f32x4*)&red[0][rr][seg * 8]     = s0;
        *(f32x4*)&red[0][rr][seg * 8 + 4] = s1;
    }
    __syncthreads();
    if (wid >= 4) return;                      // waves 4-7 done (no barriers below)

    // ---------------- phase 2: 20-step LIF recurrence (r22 trimmed form) -----
    const int lrow = wid * 16 + l15;           // waves 0-3 cover rows 0..63

    float c1[2][8], c1m1[2][8];
    #pragma unroll
    for (int kt = 0; kt < 2; ++kt) {
        f32x4 u0 = *(const f32x4*)&red[0][lrow][kt * 32 + kg];
        f32x4 u1 = *(const f32x4*)&red[0][lrow][kt * 32 + kg + 4];
        #pragma unroll
        for (int i = 0; i < 4; ++i) {
            c1[kt][i] = u0[i];     c1[kt][4 + i] = u1[i];
            c1m1[kt][i] = u0[i] - THRESH; c1m1[kt][4 + i] = u1[i] - THRESH;
        }
    }

    // W2 as fp16 hi+lo MFMA A-operand
    f16x8 W2hf[2][2], W2lf[2][2];
    #pragma unroll
    for (int rt = 0; rt < 2; ++rt)
        #pragma unroll
        for (int kt = 0; kt < 2; ++kt) {
            const float* wp = W2 + (rt * 16 + l15) * 64 + kt * 32 + kg;
            split8h(*(const f32x4*)wp, *(const f32x4*)(wp + 4), W2hf[rt][kt], W2lf[rt][kt]);
        }

    float b2v[2][4], b2m1[2][4], w3a[2][4], w3b[2][4];
    #pragma unroll
    for (int nt = 0; nt < 2; ++nt)
        #pragma unroll
        for (int j = 0; j < 4; ++j) {
            const int o = nt * 16 + g4 * 4 + j;
            b2v[nt][j]  = b2[o];
            b2m1[nt][j] = b2[o] - THRESH;
            w3a[nt][j] = W3[o];
            w3b[nt][j] = W3[32 + o];
        }

    float m1[2][8] = {};
    float m2[2][4] = {};
    const int ns = nsp[0];
    for (int s = 0; s < ns; ++s) {
        f16x8 mh[2];
        #pragma unroll
        for (int kt = 0; kt < 2; ++kt)
            #pragma unroll
            for (int i = 0; i < 8; ++i) {
                float m = m1[kt][i];
                m = __builtin_fmaf(BETA, m, (m > THRESH) ? c1m1[kt][i] : c1[kt][i]);
                m1[kt][i] = m;
                mh[kt][i] = (_Float16)m;
            }
        f32x4 a2[2][2] = {};
        #pragma unroll
        for (int rt = 0; rt < 2; ++rt)
            #pragma unroll
            for (int kt = 0; kt < 2; ++kt) {
                a2[rt][kt] = MFMA16F(W2hf[rt][kt], mh[kt], a2[rt][kt], 0, 0, 0);
                a2[rt][kt] = MFMA16F(W2lf[rt][kt], mh[kt], a2[rt][kt], 0, 0, 0);
            }
        #pragma unroll
        for (int nt = 0; nt < 2; ++nt) {
            f32x4 c2 = a2[nt][0] + a2[nt][1];
            #pragma unroll
            for (int j = 0; j < 4; ++j) {
                float m = m2[nt][j];
                m2[nt][j] = __builtin_fmaf(
                    BETA, m, c2[j] + ((m > THRESH) ? b2m1[nt][j] : b2v[nt][j]));
            }
        }
    }

    float p0 = 0.f, p1 = 0.f;
    #pragma unroll
    for (int nt = 0; nt < 2; ++nt)
        #pragma unroll
        for (int j = 0; j < 4; ++j) {
            p0 = __builtin_fmaf(m2[nt][j], w3a[nt][j], p0);
            p1 = __builtin_fmaf(m2[nt][j], w3b[nt][j], p1);
        }
    p0 += __shfl_xor(p0, 16); p0 += __shfl_xor(p0, 32);
    p1 += __shfl_xor(p1, 16); p1 += __shfl_xor(p1, 32);
    if (lane < 16) {
        const size_t row = rowBase + lrow;
        out[row * 2 + 0] = p0 + b3[0];
        out[row * 2 + 1] = p1 + b3[1];
    }
}

extern "C" void kernel_launch(void* const* d_in, const int* in_sizes, int n_in,
                              void* d_out, int out_size, void* d_ws, size_t ws_size,
                              hipStream_t stream) {
    const float* x  = (const float*)d_in[0];
    const float* W1 = (const float*)d_in[1];
    const float* b1 = (const float*)d_in[2];
    const float* W2 = (const float*)d_in[3];
    const float* b2 = (const float*)d_in[4];
    const float* W3 = (const float*)d_in[5];
    const float* b3 = (const float*)d_in[6];
    const int*   ns = (const int*)d_in[7];
    float* o = (float*)d_out;

    const int B = in_sizes[0] / KDIM;              // 16384
    _Float16* WT = (_Float16*)d_ws;                // [56][2048] fp16 (224 KB)

    w1_relayout<<<NKT2, 256, 0, stream>>>(W1, WT);
    snn_fused<<<B / 64, 512, 0, stream>>>(x, WT, b1, W2, b2, W3, b3, ns, o);
}

// Round 25
// 37.049 us; speedup vs baseline: 1.1090x; 1.0003x over previous
//
#include <hip/hip_runtime.h>
#include <hip/hip_bf16.h>

typedef float f32x4 __attribute__((ext_vector_type(4)));
typedef __fp16 h16x2 __attribute__((ext_vector_type(2)));   // cvt_pkrtz result type
typedef _Float16 f16x8 __attribute__((ext_vector_type(8)));

#define MFMA16F __builtin_amdgcn_mfma_f32_16x16x32_f16

static constexpr int KDIM = 1700;
static constexpr int NKT2 = 56;         // padded k-tiles: 54 real (53 ragged) + 2 zero
static constexpr float BETA = 0.9f;
static constexpr float THRESH = 1.0f;

// fp32 -> fp16 hi + fp16 lo (residual, RNE) — used for W2 (one-time, accuracy)
__device__ __forceinline__ void split8h(f32x4 a, f32x4 b, f16x8& hi, f16x8& lo) {
    #pragma unroll
    for (int i = 0; i < 4; ++i) {
        _Float16 h = (_Float16)a[i];
        hi[i] = h; lo[i] = (_Float16)(a[i] - (float)h);
    }
    #pragma unroll
    for (int i = 0; i < 4; ++i) {
        _Float16 h = (_Float16)b[i];
        hi[4 + i] = h; lo[4 + i] = (_Float16)(b[i] - (float)h);
    }
}

// fp32x8 -> fp16x8 via packed RTZ converts (4 instructions instead of 8)
__device__ __forceinline__ f16x8 cvt8h(f32x4 a, f32x4 b) {
    h16x2 p0 = __builtin_amdgcn_cvt_pkrtz(a[0], a[1]);
    h16x2 p1 = __builtin_amdgcn_cvt_pkrtz(a[2], a[3]);
    h16x2 p2 = __builtin_amdgcn_cvt_pkrtz(b[0], b[1]);
    h16x2 p3 = __builtin_amdgcn_cvt_pkrtz(b[2], b[3]);
    f16x8 r;
    r[0] = (_Float16)p0[0]; r[1] = (_Float16)p0[1];
    r[2] = (_Float16)p1[0]; r[3] = (_Float16)p1[1];
    r[4] = (_Float16)p2[0]; r[5] = (_Float16)p2[1];
    r[6] = (_Float16)p3[0]; r[7] = (_Float16)p3[1];
    return r;
}

// W1 [64][1700] f32 -> ONE fp16 plane in MFMA-B-fragment order, 56 k-tiles
// (k >= 1700 zero-padded).
__global__ void w1_relayout(const float* __restrict__ W1, _Float16* __restrict__ WT) {
    const int g    = blockIdx.x * 256 + threadIdx.x;   // 0 .. 56*256-1
    const int kt   = g >> 8;
    const int nt   = (g >> 6) & 3;
    const int lane = g & 63;
    const int n    = nt * 16 + (lane & 15);
    const int kb   = kt * 32 + (lane >> 4) * 8;
    f16x8 v;
    #pragma unroll
    for (int i = 0; i < 8; ++i) {
        const int k = kb + i;
        v[i] = (k < KDIM) ? (_Float16)W1[n * KDIM + k] : (_Float16)0.f;
    }
    *(f16x8*)(WT + (size_t)g * 8) = v;
}

__device__ __forceinline__ void gll16(const void* src, const void* lds_dst) {
    __builtin_amdgcn_global_load_lds(
        (const __attribute__((address_space(1))) unsigned int*)src,
        (__attribute__((address_space(3))) unsigned int*)lds_dst, 16, 0, 0);
}

// ---------------- fused kernel: cur1 GEMM (64 rows/block) + LIF --------------
// GEMM phase = r23 structure (verified 37.06us); this round: packed RTZ
// f32->f16 converts in both phases (compiler can't auto-substitute: RTZ!=RNE)
// + explicit x row-pointer hoist. Pipeline/ledger/sync UNTOUCHED.
// Ledger: prologue W0[4],x0[8],W1[4],x1[8] = 24 outstanding; steps 0-5 wait
// vmcnt(12) = drain exactly W(I)+x(I); step 6 waits 0. r14 hazard invariant:
// buf I&1 ds_reads + lgkmcnt(0) precede its restage by W(I+2).
__global__ __launch_bounds__(512, 1) void snn_fused(
    const float* __restrict__ x, const _Float16* __restrict__ WT,
    const float* __restrict__ b1, const float* __restrict__ W2,
    const float* __restrict__ b2, const float* __restrict__ W3,
    const float* __restrict__ b3, const int* __restrict__ nsp,
    float* __restrict__ out)
{
    __shared__ __align__(16) char smemraw[69632];   // W 64KB loop / red[4][64][68]
    _Float16* ldsW = (_Float16*)smemraw;
    float (*red)[64][68] = (float (*)[64][68])smemraw;

    const int tid = threadIdx.x;
    const int wid = tid >> 6;                  // 0..7 = K-eighth
    const int lane = tid & 63;
    const int l15 = lane & 15;
    const int g4  = lane >> 4;
    const int kg  = g4 * 8;
    const int rowBase = blockIdx.x * 64;
    const int tb  = wid * 7;                   // this wave's first k-tile

    const _Float16* pW = WT + (size_t)tb * 2048 + lane * 8;   // per-lane W src
    _Float16* myLds = ldsW + wid * 4096;       // 8KB/wave (2 x 4KB bufs)

    // hoisted x row-base pointers (one per 16-row group)
    const float* xrg[4];
    #pragma unroll
    for (int rg = 0; rg < 4; ++rg)
        xrg[rg] = x + (size_t)(rowBase + rg * 16 + l15) * KDIM;

    struct XB { f32x4 v[8]; };                 // 4 row-groups x 2 k-halves
    auto xload = [&](int t, XB& xb) {
        const int k1 = t * 32 + kg;
        const int kc1 = (k1 <= 1696) ? k1 : 1664;
        const int kc2 = (k1 + 4 <= 1696) ? k1 + 4 : 1664;
        #pragma unroll
        for (int rg = 0; rg < 4; ++rg) {
            const float* p0 = xrg[rg] + kc1;
            const float* p1 = xrg[rg] + kc2;
            asm volatile("global_load_dwordx4 %0, %1, off" : "=v"(xb.v[2*rg])   : "v"(p0));
            asm volatile("global_load_dwordx4 %0, %1, off" : "=v"(xb.v[2*rg+1]) : "v"(p1));
        }
    };
    auto stageW = [&](int i, int buf) {
        _Float16* dstb = myLds + buf * 2048;
        #pragma unroll
        for (int q = 0; q < 4; ++q)
            gll16(pW + (size_t)i * 2048 + q * 512, dstb + q * 512);
    };

    f32x4 acc[4][4] = {};
    XB x0, x1;

    // prologue issue order: W0, x0, W1, x1  (24 outstanding)
    stageW(0, 0); xload(tb + 0, x0);
    stageW(1, 1); xload(tb + 1, x1);

#define GSTEP(I, XC, WAITN)                                                    \
    {                                                                          \
        asm volatile("s_waitcnt vmcnt(" #WAITN ")" ::: "memory");              \
        __builtin_amdgcn_sched_barrier(0);                                     \
        const _Float16* rb = myLds + ((I) & 1) * 2048;                         \
        f16x8 WC[4];                                                           \
        _Pragma("unroll")                                                      \
        for (int q = 0; q < 4; ++q)                                            \
            WC[q] = *(const f16x8*)(rb + q * 512 + lane * 8);                  \
        f16x8 ah[4];                                                           \
        _Pragma("unroll")                                                      \
        for (int rg = 0; rg < 4; ++rg)                                         \
            ah[rg] = cvt8h(XC.v[2*rg], XC.v[2*rg+1]);                          \
        asm volatile("s_waitcnt lgkmcnt(0)" ::: "memory");                     \
        __builtin_amdgcn_sched_barrier(0);                                     \
        if constexpr ((I) + 2 < 7) { stageW((I) + 2, (I) & 1);                 \
                                     xload(tb + (I) + 2, XC); }                \
        __builtin_amdgcn_sched_barrier(0);                                     \
        _Pragma("unroll")                                                      \
        for (int mt = 0; mt < 4; ++mt)                                         \
            _Pragma("unroll")                                                  \
            for (int nt = 0; nt < 4; ++nt)                                     \
                acc[mt][nt] = MFMA16F(ah[mt], WC[nt], acc[mt][nt], 0, 0, 0);   \
    }

    GSTEP(0, x0, 12)
    GSTEP(1, x1, 12)
    GSTEP(2, x0, 12)
    GSTEP(3, x1, 12)
    GSTEP(4, x0, 12)
    GSTEP(5, x1, 12)
    GSTEP(6, x0, 0)
#undef GSTEP

    // ---- 8-partial reduction in 70KB LDS (W region dead after barrier) ------
    __syncthreads();
    if (wid >= 4) {                            // waves 4-7 dump partials
        #pragma unroll
        for (int mt = 0; mt < 4; ++mt)
            #pragma unroll
            for (int nt = 0; nt < 4; ++nt)
                #pragma unroll
                for (int j = 0; j < 4; ++j)
                    red[wid - 4][mt * 16 + g4 * 4 + j][nt * 16 + l15] = acc[mt][nt][j];
    }
    __syncthreads();
    if (wid < 4) {                             // fold partner (wid+4), write back
        #pragma unroll
        for (int mt = 0; mt < 4; ++mt)
            #pragma unroll
            for (int nt = 0; nt < 4; ++nt)
                #pragma unroll
                for (int j = 0; j < 4; ++j) {
                    float v = acc[mt][nt][j]
                            + red[wid][mt * 16 + g4 * 4 + j][nt * 16 + l15];
                    red[wid][mt * 16 + g4 * 4 + j][nt * 16 + l15] = v;
                }
    }
    __syncthreads();
    // final fold of 4 + b1 -> red[0]; 512 tasks = 64 rows x 8 segs, disjoint
    {
        const int rr  = tid >> 3;
        const int seg = tid & 7;
        f32x4 s0 = *(const f32x4*)(b1 + seg * 8);
        f32x4 s1 = *(const f32x4*)(b1 + seg * 8 + 4);
        #pragma unroll
        for (int p = 0; p < 4; ++p) {
            s0 += *(const f32x4*)&red[p][rr][seg * 8];
            s1 += *(const f32x4*)&red[p][rr][seg * 8 + 4];
        }
        *(f32x4*)&red[0][rr][seg * 8]     = s0;
        *(f32x4*)&red[0][rr][seg * 8 + 4] = s1;
    }
    __syncthreads();
    if (wid >= 4) return;                      // waves 4-7 done (no barriers below)

    // ---------------- phase 2: 20-step LIF recurrence (trimmed form) ---------
    const int lrow = wid * 16 + l15;           // waves 0-3 cover rows 0..63

    float c1[2][8], c1m1[2][8];
    #pragma unroll
    for (int kt = 0; kt < 2; ++kt) {
        f32x4 u0 = *(const f32x4*)&red[0][lrow][kt * 32 + kg];
        f32x4 u1 = *(const f32x4*)&red[0][lrow][kt * 32 + kg + 4];
        #pragma unroll
        for (int i = 0; i < 4; ++i) {
            c1[kt][i] = u0[i];     c1[kt][4 + i] = u1[i];
            c1m1[kt][i] = u0[i] - THRESH; c1m1[kt][4 + i] = u1[i] - THRESH;
        }
    }

    // W2 as fp16 hi+lo MFMA A-operand (RNE split, one-time)
    f16x8 W2hf[2][2], W2lf[2][2];
    #pragma unroll
    for (int rt = 0; rt < 2; ++rt)
        #pragma unroll
        for (int kt = 0; kt < 2; ++kt) {
            const float* wp = W2 + (rt * 16 + l15) * 64 + kt * 32 + kg;
            split8h(*(const f32x4*)wp, *(const f32x4*)(wp + 4), W2hf[rt][kt], W2lf[rt][kt]);
        }

    float b2v[2][4], b2m1[2][4], w3a[2][4], w3b[2][4];
    #pragma unroll
    for (int nt = 0; nt < 2; ++nt)
        #pragma unroll
        for (int j = 0; j < 4; ++j) {
            const int o = nt * 16 + g4 * 4 + j;
            b2v[nt][j]  = b2[o];
            b2m1[nt][j] = b2[o] - THRESH;
            w3a[nt][j] = W3[o];
            w3b[nt][j] = W3[32 + o];
        }

    float m1[2][8] = {};
    float m2[2][4] = {};
    const int ns = nsp[0];
    for (int s = 0; s < ns; ++s) {
        // mem1 update + packed RTZ fp16 quantization (2 elems/instr)
        f16x8 mh[2];
        #pragma unroll
        for (int kt = 0; kt < 2; ++kt)
            #pragma unroll
            for (int i = 0; i < 8; i += 2) {
                float ma = m1[kt][i];
                ma = __builtin_fmaf(BETA, ma, (ma > THRESH) ? c1m1[kt][i] : c1[kt][i]);
                m1[kt][i] = ma;
                float mb = m1[kt][i + 1];
                mb = __builtin_fmaf(BETA, mb, (mb > THRESH) ? c1m1[kt][i + 1] : c1[kt][i + 1]);
                m1[kt][i + 1] = mb;
                h16x2 p = __builtin_amdgcn_cvt_pkrtz(ma, mb);
                mh[kt][i] = (_Float16)p[0]; mh[kt][i + 1] = (_Float16)p[1];
            }
        f32x4 a2[2][2] = {};
        #pragma unroll
        for (int rt = 0; rt < 2; ++rt)
            #pragma unroll
            for (int kt = 0; kt < 2; ++kt) {
                a2[rt][kt] = MFMA16F(W2hf[rt][kt], mh[kt], a2[rt][kt], 0, 0, 0);
                a2[rt][kt] = MFMA16F(W2lf[rt][kt], mh[kt], a2[rt][kt], 0, 0, 0);
            }
        #pragma unroll
        for (int nt = 0; nt < 2; ++nt) {
            f32x4 c2 = a2[nt][0] + a2[nt][1];
            #pragma unroll
            for (int j = 0; j < 4; ++j) {
                float m = m2[nt][j];
                m2[nt][j] = __builtin_fmaf(
                    BETA, m, c2[j] + ((m > THRESH) ? b2m1[nt][j] : b2v[nt][j]));
            }
        }
    }

    float p0 = 0.f, p1 = 0.f;
    #pragma unroll
    for (int nt = 0; nt < 2; ++nt)
        #pragma unroll
        for (int j = 0; j < 4; ++j) {
            p0 = __builtin_fmaf(m2[nt][j], w3a[nt][j], p0);
            p1 = __builtin_fmaf(m2[nt][j], w3b[nt][j], p1);
        }
    p0 += __shfl_xor(p0, 16); p0 += __shfl_xor(p0, 32);
    p1 += __shfl_xor(p1, 16); p1 += __shfl_xor(p1, 32);
    if (lane < 16) {
        const size_t row = rowBase + lrow;
        out[row * 2 + 0] = p0 + b3[0];
        out[row * 2 + 1] = p1 + b3[1];
    }
}

extern "C" void kernel_launch(void* const* d_in, const int* in_sizes, int n_in,
                              void* d_out, int out_size, void* d_ws, size_t ws_size,
                              hipStream_t stream) {
    const float* x  = (const float*)d_in[0];
    const float* W1 = (const float*)d_in[1];
    const float* b1 = (const float*)d_in[2];
    const float* W2 = (const float*)d_in[3];
    const float* b2 = (const float*)d_in[4];
    const float* W3 = (const float*)d_in[5];
    const float* b3 = (const float*)d_in[6];
    const int*   ns = (const int*)d_in[7];
    float* o = (float*)d_out;

    const int B = in_sizes[0] / KDIM;              // 16384
    _Float16* WT = (_Float16*)d_ws;                // [56][2048] fp16 (224 KB)

    w1_relayout<<<NKT2, 256, 0, stream>>>(W1, WT);
    snn_fused<<<B / 64, 512, 0, stream>>>(x, WT, b1, W2, b2, W3, b3, ns, o);
}